// Round 16
// baseline (26.728 us; speedup 1.0000x reference)
//
#include <hip/hip_runtime.h>
#include <stdint.h>

// Problem: x (4096,2048) int32 {0,1}; references (1024,2048) f32 {0,1};
// out (4096,1024) f32 = (hamming - 1024) / (0.5*sqrt(2048)).
// Identity: s=1-2x, t=1-2r in {+-1}: hamming = (2048 - s.t)/2 ->
//   out[b,d] = -(inv_std/2) * dot_pm1(b,d)     (exact integer dot)
// fp4 E2M1: +1=0x2, -1=0xA; MX scales all 1.0 (E8M0 0x7F) -> exact f32 dot.
constexpr int B_ROWS = 4096;
constexpr int D_ROWS = 1024;
constexpr int L_LEN  = 2048;

using int32x4 = __attribute__((ext_vector_type(4))) int;
using int32x8 = __attribute__((ext_vector_type(8))) int;
using f32x16  = __attribute__((ext_vector_type(16))) float;

// ---------------------------------------------------------------------------
// Kernel 1 (R6's transposed ballot-pack, VERBATIM — proven <=9.2us incl gap
// in R5/R6): pack to 1 bit/elem in pair-plane layout xp2[p][row], p=0..15.
// Each ulonglong2 entry = 128 bits = exactly one GEMM K-step of one row.
// The word permutation is row-uniform and identical for x and refs -> it is
// a shared K-permutation -> the +-1 dot is exactly preserved.
// ---------------------------------------------------------------------------
__global__ __launch_bounds__(256) void pack_bits_kernel(
    const int* __restrict__ x, const float* __restrict__ r,
    ulonglong2* __restrict__ xp2, ulonglong2* __restrict__ rp2,
    int groups_x, int groups_total)
{
  const int lane   = threadIdx.x & 63;
  const int wave   = (int)((blockIdx.x * blockDim.x + threadIdx.x) >> 6);
  const int nwaves = (int)((gridDim.x * blockDim.x) >> 6);

  for (int g = wave; g < groups_total; g += nwaves) {   // g is wave-uniform
    if (g < groups_x) {
      const int4 v = *reinterpret_cast<const int4*>(x + (size_t)g * 256 + lane * 4);
      uint64_t m0 = __ballot(v.x != 0);
      uint64_t m1 = __ballot(v.y != 0);
      uint64_t m2 = __ballot(v.z != 0);
      uint64_t m3 = __ballot(v.w != 0);
      if (lane == 0) {
        const int row = g >> 3;
        const int p   = (g & 7) * 2;
        ulonglong2 a; a.x = m0; a.y = m1;
        ulonglong2 b; b.x = m2; b.y = m3;
        xp2[(size_t)p       * B_ROWS + row] = a;
        xp2[(size_t)(p + 1) * B_ROWS + row] = b;
      }
    } else {
      const int gr = g - groups_x;
      const float4 v = *reinterpret_cast<const float4*>(r + (size_t)gr * 256 + lane * 4);
      uint64_t m0 = __ballot(v.x != 0.0f);
      uint64_t m1 = __ballot(v.y != 0.0f);
      uint64_t m2 = __ballot(v.z != 0.0f);
      uint64_t m3 = __ballot(v.w != 0.0f);
      if (lane == 0) {
        const int row = gr >> 3;
        const int p   = (gr & 7) * 2;
        ulonglong2 a; a.x = m0; a.y = m1;
        ulonglong2 b; b.x = m2; b.y = m3;
        rp2[(size_t)p       * D_ROWS + row] = a;
        rp2[(size_t)(p + 1) * D_ROWS + row] = b;
      }
    }
  }
}

// ---------------------------------------------------------------------------
// Kernel 2: MX-fp4 GEMM (R12 geometry + MFMA phase), staging = packed bits ->
// in-register nibble expansion -> swizzled ds_write. No 5MB fp4 buffer, no
// global_load_lds. Per wave per K-step:
//   loads: A 512 B contiguous (uint64/lane), B 256 B contiguous (dword/lane)
//   expand: dword -> 4 fp4 dwords via 5-op bit-deposit (nibble 0x2|bit<<3)
//   ds_write_b128 x3 (slots balanced across bank-quads, ~floor)
//   then 6 ds_read_b128 + 4 mfma_scale_f32_32x32x64_f8f6f4 (unchanged)
// Pipeline: 2 LDS buffers, reg sets ping-pong; per step: issue loads ks+2,
// expand tile ks+1 -> buf[nxt], compute buf[cur], lgkmcnt(0)+raw barrier.
// Safety: writes@ks to buf[nxt] vs reads@ks+1 separated by barrier@ks (with
// lgkmcnt(0) drain); reads@ks of buf[cur] complete before barrier@ks (MFMA
// data-dep), writes to that buffer happen only after barrier@ks. Compiler's
// automatic vmcnt covers the reg-staged loads (dataflow-tracked).
// ---------------------------------------------------------------------------
constexpr int BM = 128;
constexpr int BN = 64;
constexpr int BKB = 64;                  // K-step bytes per row (128 elems)
constexpr int KSTEPS = 16;
constexpr int GRID_D = D_ROWS / BN;      // 16
constexpr int NWG = (B_ROWS / BM) * GRID_D;   // 512

__device__ __forceinline__ uint32_t dep8(uint32_t t) {
  // spread 8 bits to positions 3,7,...,31 and OR the +1 pattern:
  uint32_t v = (t | (t << 12)) & 0x000F000Fu;
  v = (v | (v << 6)) & 0x03030303u;
  v = (v | (v << 3)) & 0x11111111u;
  return 0x22222222u | (v << 3);         // bit=0 -> 0x2 (+1), bit=1 -> 0xA (-1)
}
__device__ __forceinline__ int32x4 expand32(uint32_t wbits) {
  int32x4 o;
  o[0] = (int)dep8(wbits & 0xFFu);
  o[1] = (int)dep8((wbits >> 8) & 0xFFu);
  o[2] = (int)dep8((wbits >> 16) & 0xFFu);
  o[3] = (int)dep8(wbits >> 24);
  return o;
}

__global__ __launch_bounds__(256) void gemm_fp4_kernel(
    const uint64_t* __restrict__ xp, const uint32_t* __restrict__ rp,
    float* __restrict__ out)
{
  __shared__ __align__(16) uint8_t A_lds[2][BM * BKB];   // 2 x 8 KB
  __shared__ __align__(16) uint8_t B_lds[2][BN * BKB];   // 2 x 4 KB

  const int lin = blockIdx.x;
  const int swz = (lin & 7) * (NWG / 8) + (lin >> 3);   // bijective, 512%8==0
  const int bm  = (swz / GRID_D) * BM;
  const int bn  = (swz % GRID_D) * BN;

  const int t    = threadIdx.x;
  const int lane = t & 63;
  const int w    = t >> 6;          // wave 0..3
  const int wr   = w >> 1;          // wave row (m)
  const int wc   = w & 1;           // wave col (n)

  // Staging coordinates. A: 32 rows/wave, 2 lanes/row (one uint64 half each);
  // B: 16 rows/wave, 4 lanes/row (one dword each).
  const int rA  = w * 32 + (lane >> 1);
  const int hA  = lane & 1;             // uint64 half -> slots 2hA, 2hA+1
  const int qA0 = 2 * hA;
  const int sA  = (rA >> 1) & 3;        // LDS slot swizzle (matches read side)
  const int rB  = w * 16 + (lane >> 2);
  const int qB  = lane & 3;
  const int sB  = (rB >> 1) & 3;

  // Plane layout: entry (plane ks, row) at 16B offset (ks*ROWS + row).
  const uint64_t* gA = xp + ((size_t)(bm + rA)) * 2 + hA;   // += ks*4096*2
  const uint32_t* gB = rp + ((size_t)(bn + rB)) * 4 + qB;   // += ks*1024*4

#define UNPACK_TO(buf, aset) do {                                             \
    *reinterpret_cast<int32x4*>(A_lds[buf] + rA * 64 + ((qA0 ^ sA) * 16)) =   \
        expand32((uint32_t)a_reg[aset]);                                      \
    *reinterpret_cast<int32x4*>(A_lds[buf] + rA * 64 + (((qA0+1) ^ sA) * 16)) \
        = expand32((uint32_t)(a_reg[aset] >> 32));                            \
    *reinterpret_cast<int32x4*>(B_lds[buf] + rB * 64 + ((qB ^ sB) * 16)) =    \
        expand32(b_reg[aset]);                                                \
  } while (0)

#define COMPUTE(cur) do {                                                     \
    _Pragma("unroll") for (int kc = 0; kc < 2; ++kc) {                        \
      const int rowB = wc * 32 + (lane & 31);                                 \
      const int qq   = 2 * kc + (lane >> 5);                                  \
      const int32x4 b4 = *reinterpret_cast<const int32x4*>(                   \
          B_lds[cur] + rowB * 64 + ((qq ^ ((rowB >> 1) & 3)) * 16));          \
      const int32x8 b8 = {b4[0], b4[1], b4[2], b4[3], 0, 0, 0, 0};            \
      _Pragma("unroll") for (int f = 0; f < 2; ++f) {                         \
        const int rowA = wr * 64 + f * 32 + (lane & 31);                      \
        const int32x4 a4 = *reinterpret_cast<const int32x4*>(                 \
            A_lds[cur] + rowA * 64 + ((qq ^ ((rowA >> 1) & 3)) * 16));        \
        const int32x8 a8 = {a4[0], a4[1], a4[2], a4[3], 0, 0, 0, 0};          \
        acc[f] = __builtin_amdgcn_mfma_scale_f32_32x32x64_f8f6f4(             \
            a8, b8, acc[f], 4, 4, 0, 0x7F7F7F7F, 0, 0x7F7F7F7F);              \
      }                                                                       \
    } } while (0)

  f32x16 acc[2] = {};
  uint64_t a_reg[2];
  uint32_t b_reg[2];

  // Prologue: load tiles 0,1; expand tile 0 into buf 0; publish.
  a_reg[0] = gA[0];            b_reg[0] = gB[0];
  a_reg[1] = gA[8192];         b_reg[1] = gB[4096];
  UNPACK_TO(0, 0);
  asm volatile("s_waitcnt lgkmcnt(0)" ::: "memory");
  __builtin_amdgcn_sched_barrier(0);
  __builtin_amdgcn_s_barrier();

#pragma unroll
  for (int ks = 0; ks < KSTEPS; ++ks) {
    const int cur = ks & 1;
    const int nxt = cur ^ 1;
    if (ks < KSTEPS - 1) {
      if (ks + 2 < KSTEPS) {   // refill the reg set freed last iteration
        a_reg[cur] = gA[(size_t)(ks + 2) * 8192];
        b_reg[cur] = gB[(size_t)(ks + 2) * 4096];
      }
      UNPACK_TO(nxt, nxt);     // expand tile ks+1 (compiler waits its loads)
    }
    COMPUTE(cur);
    asm volatile("s_waitcnt lgkmcnt(0)" ::: "memory");  // writes drained
    __builtin_amdgcn_sched_barrier(0);                  // rule #18
    __builtin_amdgcn_s_barrier();                       // publish buf[nxt]
  }
#undef UNPACK_TO
#undef COMPUTE

  // Epilogue: verified 32x32 C/D layout: col = lane&31,
  // row = (reg&3) + 8*(reg>>2) + 4*(lane>>5).
  const float scale = -0.5f * 0.04419417382415922f;
  const int col = bn + wc * 32 + (lane & 31);
#pragma unroll
  for (int f = 0; f < 2; ++f) {
#pragma unroll
    for (int reg = 0; reg < 16; ++reg) {
      const int row = bm + wr * 64 + f * 32 + (reg & 3) + 8 * (reg >> 2)
                    + 4 * (lane >> 5);
      out[(size_t)row * D_ROWS + col] = acc[f][reg] * scale;
    }
  }
}

extern "C" void kernel_launch(void* const* d_in, const int* in_sizes, int n_in,
                              void* d_out, int out_size, void* d_ws, size_t ws_size,
                              hipStream_t stream) {
  const int*   x = (const int*)d_in[0];     // (4096, 2048) int32
  const float* r = (const float*)d_in[1];   // (1024, 2048) float32
  float*     out = (float*)d_out;           // (4096, 1024) float32

  ulonglong2* xp2 = (ulonglong2*)d_ws;                      // 1 MiB packed A
  ulonglong2* rp2 = xp2 + (size_t)16 * B_ROWS;              // 256 KiB packed B

  const int groups_x = B_ROWS * L_LEN / 256;                // 32768
  const int groups_r = D_ROWS * L_LEN / 256;                // 8192
  const int groups_total = groups_x + groups_r;             // 40960

  pack_bits_kernel<<<2048, 256, 0, stream>>>(x, r, xp2, rp2,
                                             groups_x, groups_total);

  gemm_fp4_kernel<<<NWG, 256, 0, stream>>>(
      (const uint64_t*)xp2, (const uint32_t*)rp2, out);    // 512 blocks
}